// Round 1
// 176.461 us; speedup vs baseline: 1.0341x; 1.0341x over previous
//
#include <hip/hip_runtime.h>

typedef __bf16 bf16x8 __attribute__((ext_vector_type(8)));
typedef __bf16 bf16x4 __attribute__((ext_vector_type(4)));
typedef float  f32x4  __attribute__((ext_vector_type(4)));

#define MFMA_BF16(a, b, c) __builtin_amdgcn_mfma_f32_16x16x32_bf16((a), (b), (c), 0, 0, 0)
#define NEG_INF (-1e30f)
// softmax scale folded with log2(e): exp(s*0.125) == exp2(s*0.125*1.442695)
#define SCL 0.18033688f

__device__ __forceinline__ void gld16(const void* g, void* l) {
  __builtin_amdgcn_global_load_lds(
      (const __attribute__((address_space(1))) void*)g,
      (__attribute__((address_space(3))) void*)l, 16, 0, 0);
}

// ---------------------------------------------------------------------------
// Cast fp32 -> bf16, 8 elems/thread.
// ---------------------------------------------------------------------------
__global__ void cast_f32_bf16(const float* __restrict__ in,
                              __bf16* __restrict__ out, int n) {
  int i = (blockIdx.x * 256 + threadIdx.x) * 8;
  if (i >= n) return;
  float4 a = *(const float4*)&in[i];
  float4 b = *(const float4*)&in[i + 4];
  bf16x8 v;
  v[0] = (__bf16)a.x; v[1] = (__bf16)a.y; v[2] = (__bf16)a.z; v[3] = (__bf16)a.w;
  v[4] = (__bf16)b.x; v[5] = (__bf16)b.y; v[6] = (__bf16)b.z; v[7] = (__bf16)b.w;
  *(bf16x8*)&out[i] = v;
}

// ---------------------------------------------------------------------------
// Transpose: in [R][C] fp32 -> out [C][R] bf16. 32x32 tiles, 256 threads.
// ---------------------------------------------------------------------------
__global__ void transpose_f32_bf16(const float* __restrict__ in,
                                   __bf16* __restrict__ out, int R, int C) {
  __shared__ float t[32][33];
  int tx = threadIdx.x & 31, ty = threadIdx.x >> 5;  // 32 x 8
  int x = blockIdx.x * 32 + tx;
  int y0 = blockIdx.y * 32 + ty;
#pragma unroll
  for (int i = 0; i < 4; ++i)
    t[ty + 8 * i][tx] = in[(size_t)(y0 + 8 * i) * C + x];
  __syncthreads();
  int x2 = blockIdx.y * 32 + tx;
#pragma unroll
  for (int i = 0; i < 4; ++i)
    out[(size_t)(blockIdx.x * 32 + ty + 8 * i) * R + x2] = (__bf16)t[tx][ty + 8 * i];
}

// ---------------------------------------------------------------------------
// GEMM: C[M][N] = A[M][K]*Bt[N][K]^T + bias[N]. A,Bt bf16, fp32 accum.
// m97 structure + XOR-swizzled LDS (source-permuted gld16; conflict-free).
// Still used for the proj GEMM (N=1024 doesn't fit the 256x192 grid well).
// ---------------------------------------------------------------------------
#define BN 128
#define BK 64

template <int BMT, typename TC>
__global__ __launch_bounds__(256) void gemm_bt_bias(
    const __bf16* __restrict__ A, const __bf16* __restrict__ Bt,
    const float* __restrict__ bias, TC* __restrict__ Cmat,
    int M, int N, int K) {
  constexpr int NI = BMT / 32;  // A chunks per thread; MFMA row-tiles per wave
  __shared__ __align__(16) __bf16 As[BMT * BK];
  __shared__ __align__(16) __bf16 Bs[BN * BK];
  int tid = threadIdx.x;
  int wave = tid >> 6, lane = tid & 63;
  int l16 = lane & 15, quad = lane >> 4;
  int wm = wave >> 1, wn = wave & 1;
  int m0 = blockIdx.y * BMT, n0 = blockIdx.x * BN;

  f32x4 acc[NI][4];
#pragma unroll
  for (int i = 0; i < NI; ++i)
#pragma unroll
    for (int j = 0; j < 4; ++j) acc[i][j] = (f32x4){0.f, 0.f, 0.f, 0.f};

  int row = tid >> 3;                                // 0..31 (+32*i)
  // swizzled source column: slot (tid&7) of row r fetches chunk (tid&7)^(r&7)
  int kc = ((tid & 7) ^ ((tid >> 3) & 7)) * 8;       // i*32 doesn't change r&7
  // fragment-read xor key (elements): chunk cc -> slot cc^(l16&7)
  int xr = (l16 & 7) * 8;

  for (int k0 = 0; k0 < K; k0 += BK) {
#pragma unroll
    for (int i = 0; i < NI; ++i)
      gld16(&A[(size_t)(m0 + row + i * 32) * K + k0 + kc],
            (char*)As + (i * 256 + wave * 64) * 16);
#pragma unroll
    for (int j = 0; j < 4; ++j)
      gld16(&Bt[(size_t)(n0 + row + j * 32) * K + k0 + kc],
            (char*)Bs + (j * 256 + wave * 64) * 16);
    __syncthreads();
#pragma unroll
    for (int ks = 0; ks < 2; ++ks) {
      bf16x8 af[NI], bfr[4];
#pragma unroll
      for (int i = 0; i < NI; ++i)
        af[i] = *(const bf16x8*)&As[(wm * (BMT / 2) + i * 16 + l16) * BK +
                                    ((ks * 32 + quad * 8) ^ xr)];
#pragma unroll
      for (int j = 0; j < 4; ++j)
        bfr[j] = *(const bf16x8*)&Bs[(wn * 64 + j * 16 + l16) * BK +
                                     ((ks * 32 + quad * 8) ^ xr)];
#pragma unroll
      for (int i = 0; i < NI; ++i)
#pragma unroll
        for (int j = 0; j < 4; ++j) acc[i][j] = MFMA_BF16(af[i], bfr[j], acc[i][j]);
    }
    __syncthreads();
  }
  // epilogue: D row = quad*4+r, col = lane&15 within each 16x16 tile
#pragma unroll
  for (int i = 0; i < NI; ++i) {
#pragma unroll
    for (int j = 0; j < 4; ++j) {
      int col = n0 + wn * 64 + j * 16 + l16;
      float bv = bias[col];
#pragma unroll
      for (int r = 0; r < 4; ++r) {
        int rw = m0 + wm * (BMT / 2) + i * 16 + quad * 4 + r;
        Cmat[(size_t)rw * N + col] = (TC)(acc[i][j][r] + bv);
      }
    }
  }
}

// ---------------------------------------------------------------------------
// 8-phase qkv GEMM: C[4096][3072] = A[4096][1024] * Bt[3072][1024]^T + bias.
// 256x192 tile, 512 threads (8 waves, 2M x 4N), BK=64 as two K=32 halves.
// Grid 16x16 = 256 blocks = exactly 1 block/CU.
// T2: LDS swizzle (chunk ^= (row>>1)&3; bank-verified 2-way = free) applied
//     source-side for global_load_lds (rule: linear dest + inv-swz source).
// T3+T4: 8 phases/iter (2 K-tiles), counted vmcnt(4) only at phases 4 & 8.
// T5: setprio(1) around each 12-MFMA cluster.
// Staging schedule (iter i computes u=2i from buf0 ph1-4, v=2i+1 from buf1
// ph5-8; one half-tile DMA per phase):
//   ph1: A(v,ks1)->buf1   ph2: B(v,ks1)   ph3: A(2i+2,ks0)->buf0
//   ph4: B(2i+2,ks0)+WVM4 ph5: A(2i+2,ks1) ph6: B(2i+2,ks1)
//   ph7: A(2i+3,ks0)->buf1 ph8: B(2i+3,ks0)+WVM4
// Freshness: each region is re-staged exactly one closing-barrier after its
// last reader's lgkmcnt(0). vmcnt(4) leaves only the 2 newest half-tiles in
// flight; every tile's halves are older than that at its consume point.
// Epilogue fuses the V transpose: cols >= 2048 go to vt[bh*64+d][t] directly.
// ---------------------------------------------------------------------------
#define BARX do { asm volatile("" ::: "memory"); __builtin_amdgcn_s_barrier(); \
                  asm volatile("" ::: "memory"); } while (0)
#define WLGKM do { asm volatile("s_waitcnt lgkmcnt(0)" ::: "memory"); \
                   __builtin_amdgcn_sched_barrier(0); } while (0)
#define WVM4 asm volatile("s_waitcnt vmcnt(4)" ::: "memory")
#define STA8(SBUF, SKS, T) do { \
    gld16(srcA1 + (size_t)(T) * 64 + (SKS) * 32, (char*)&As[SBUF][SKS][0] + tid * 16); \
    gld16(srcA2 + (size_t)(T) * 64 + (SKS) * 32, (char*)&As[SBUF][SKS][0] + tid * 16 + 8192); \
  } while (0)
#define STB8(SBUF, SKS, T) do { \
    gld16(srcB1 + (size_t)(T) * 64 + (SKS) * 32, (char*)&Bs[SBUF][SKS][0] + tid * 16); \
    gld16(srcB2 + (size_t)(T) * 64 + (SKS) * 32, (char*)&Bs[SBUF][SKS][0] + tid * 16 + 8192); \
  } while (0)
#define LDA4(CBUF, CKS, MQ) do { \
    const __bf16* p_ = &As[CBUF][CKS][(wm * 128 + (MQ) * 64 + l16) * 32 + xrd]; \
    af[0] = *(const bf16x8*)(p_);        af[1] = *(const bf16x8*)(p_ + 512); \
    af[2] = *(const bf16x8*)(p_ + 1024); af[3] = *(const bf16x8*)(p_ + 1536); \
  } while (0)
#define LDB3(CBUF, CKS) do { \
    const __bf16* p_ = &Bs[CBUF][CKS][(wn * 48 + l16) * 32 + xrd]; \
    bfr[0] = *(const bf16x8*)(p_);       bfr[1] = *(const bf16x8*)(p_ + 512); \
    bfr[2] = *(const bf16x8*)(p_ + 1024); \
  } while (0)
#define MM12(MQ) do { \
    __builtin_amdgcn_s_setprio(1); \
    _Pragma("unroll") for (int mi_ = 0; mi_ < 4; ++mi_) \
    _Pragma("unroll") for (int nj_ = 0; nj_ < 3; ++nj_) \
      acc[(MQ) * 4 + mi_][nj_] = MFMA_BF16(af[mi_], bfr[nj_], acc[(MQ) * 4 + mi_][nj_]); \
    __builtin_amdgcn_s_setprio(0); \
  } while (0)

__global__ __launch_bounds__(512, 2) void gemm_qkv_8ph(
    const __bf16* __restrict__ A, const __bf16* __restrict__ Bt,
    const float* __restrict__ bias, __bf16* __restrict__ qkv,
    __bf16* __restrict__ vt) {
  constexpr int GK = 1024, GN = 3072, NT = 16;  // K, N, K-tiles
  // [buf][khalf][row*32+col]; 16 KiB per region, 128 KiB total.
  __shared__ __align__(16) __bf16 As[2][2][256 * 32];
  __shared__ __align__(16) __bf16 Bs[2][2][256 * 32];  // rows 192..255 = pad
  const int tid = threadIdx.x;
  const int wave = tid >> 6, lane = tid & 63;
  const int l16 = lane & 15, quad = lane >> 4;
  const int wm = wave >> 2, wn = wave & 3;
  const int m0 = blockIdx.y * 256, n0 = blockIdx.x * 192;

  // staging: thread -> (row=tid>>2, slot=tid&3); source chunk = slot^((row>>1)&3)
  const int row0 = tid >> 2;                       // 0..127 (+128 on call 2)
  const int kc = (((tid & 3) ^ ((row0 >> 1) & 3)) * 8);
  // fragment-read xor key: chunk = quad ^ ((row>>1)&3); row>>1 dep reduces to l16
  const int xrd = (quad ^ ((l16 >> 1) & 3)) * 8;

  const __bf16* srcA1 = A + (size_t)(m0 + row0) * GK + kc;
  const __bf16* srcA2 = srcA1 + (size_t)128 * GK;
  const __bf16* srcB1 = Bt + (size_t)(n0 + row0) * GK + kc;
  const int br2 = (row0 + 128 < 192) ? row0 + 128 : 191;  // clamp pad rows
  const __bf16* srcB2 = Bt + (size_t)(n0 + br2) * GK + kc;

  f32x4 acc[8][3];
#pragma unroll
  for (int m = 0; m < 8; ++m)
#pragma unroll
    for (int n = 0; n < 3; ++n) acc[m][n] = (f32x4){0.f, 0.f, 0.f, 0.f};

  // prologue: tile0 (both halves) + tile1 ks0; wait tile0, keep t1ks0 in flight
  STA8(0, 0, 0); STB8(0, 0, 0);
  STA8(0, 1, 0); STB8(0, 1, 0);
  STA8(1, 0, 1); STB8(1, 0, 1);
  WVM4;
  BARX;

  bf16x8 af[4], bfr[3];
#pragma unroll 1
  for (int i = 0; i < NT / 2; ++i) {
    const int v = 2 * i + 1;
    const int t2 = (2 * i + 2 < NT) ? 2 * i + 2 : NT - 1;  // clamped: junk
    const int t3 = (2 * i + 3 < NT) ? 2 * i + 3 : NT - 1;  // staged, never read
    // ph1: compute (buf0, ks0, Mquad0)
    LDA4(0, 0, 0); LDB3(0, 0); STA8(1, 1, v);
    BARX; WLGKM; MM12(0); BARX;
    // ph2: (buf0, ks0, Mquad1); B frags reused
    LDA4(0, 0, 1); STB8(1, 1, v);
    BARX; WLGKM; MM12(1); BARX;
    // ph3: (buf0, ks1, Mquad0); buf0.ks0 free after ph2 -> restage
    LDA4(0, 1, 0); LDB3(0, 1); STA8(0, 0, t2);
    BARX; WLGKM; MM12(0); BARX;
    // ph4: (buf0, ks1, Mquad1); counted wait: tile v fully landed, 2 halves in flight
    LDA4(0, 1, 1); STB8(0, 0, t2);
    BARX; WLGKM; MM12(1); WVM4; BARX;
    // ph5: (buf1, ks0, Mquad0); buf0.ks1 free after ph4 -> restage
    LDA4(1, 0, 0); LDB3(1, 0); STA8(0, 1, t2);
    BARX; WLGKM; MM12(0); BARX;
    // ph6
    LDA4(1, 0, 1); STB8(0, 1, t2);
    BARX; WLGKM; MM12(1); BARX;
    // ph7: (buf1, ks1, Mquad0); buf1.ks0 free after ph6 -> restage
    LDA4(1, 1, 0); LDB3(1, 1); STA8(1, 0, t3);
    BARX; WLGKM; MM12(0); BARX;
    // ph8; counted wait: tile 2i+2 fully landed for next iteration's ph1
    LDA4(1, 1, 1); STB8(1, 0, t3);
    BARX; WLGKM; MM12(1); WVM4; BARX;
  }

  // epilogue: D row = quad*4+r (M), col = l16 (N). V cols write vt directly.
#pragma unroll
  for (int n = 0; n < 3; ++n) {
    const int c0 = n0 + wn * 48 + n * 16;  // wave-uniform; 2048 is 16-aligned
    const int col = c0 + l16;
    const float bv = bias[col];
    if (c0 < 2048) {
#pragma unroll
      for (int m = 0; m < 8; ++m) {
        const int rw = m0 + wm * 128 + m * 16 + quad * 4;
#pragma unroll
        for (int r = 0; r < 4; ++r)
          qkv[(size_t)(rw + r) * GN + col] = (__bf16)(acc[m][n][r] + bv);
      }
    } else {
      const int h = (col - 2048) >> 6, d = col & 63;
#pragma unroll
      for (int m = 0; m < 8; ++m) {
        const int t0 = m0 + wm * 128 + m * 16 + quad * 4;
        const int b = t0 >> 11, tt = t0 & 2047;
        bf16x4 pb;
#pragma unroll
        for (int r = 0; r < 4; ++r) pb[r] = (__bf16)(acc[m][n][r] + bv);
        *(bf16x4*)&vt[(size_t)((b * 16 + h) * 64 + d) * 2048 + tt] = pb;
      }
    }
  }
}

// ---------------------------------------------------------------------------
// Causal flash attention, no-max softmax, S^T formulation. qkv [B*T][3C] bf16,
// vt [bh*64+dim][2048 keys] bf16 (pre-transposed V, written by gemm_qkv_8ph).
// Grid (32=bh, 16=pair): block does qt=pair then 31-pair => uniform 33 iters,
// 512 blocks = 2/CU for the whole duration.
// Both K and V staged via global_load_lds DMA with source-XOR swizzle.
// S^T = K Q^T -> P^T regs -> b64 Ps stores; single barrier.
// ---------------------------------------------------------------------------
__global__ __launch_bounds__(256) void attn_causal(
    const __bf16* __restrict__ qkv, const __bf16* __restrict__ vt,
    __bf16* __restrict__ y) {
  __shared__ __align__(16) __bf16 Kb[2][64 * 64];   // [key][dimchunk^(key&7)]
  __shared__ __align__(16) __bf16 Vb[2][64 * 64];   // [dim][keychunk^(dim&7)]
  __shared__ __align__(16) __bf16 Ps[4][16 * 72];   // per-wave P [qrow16][key]
  const int tid = threadIdx.x;
  const int wave = tid >> 6, lane = tid & 63;
  const int l16 = lane & 15, quad = lane >> 4;
  const int bh = blockIdx.x;
  const int b = bh >> 4, h = bh & 15;
  const int RS = 3072;

  const int row0 = tid >> 3;                        // 0..31 (+32 for chunk 1)
  const int kcs = ((tid & 7) ^ ((tid >> 3) & 7)) * 8;  // source-permuted col
  const int xr = (l16 & 7) * 8;                     // frag-read xor key
  const __bf16* kbase = qkv + (size_t)(b * 2048) * RS + 1024 + h * 64 + kcs;
  const __bf16* vbase = vt + (size_t)(bh * 64) * 2048 + kcs;

#pragma unroll 1
  for (int phase = 0; phase < 2; ++phase) {
    const int qt = phase ? (31 - (int)blockIdx.y) : (int)blockIdx.y;

    // Q fragment: dual-use A/B layout [free=l16][k=quad*8+j]
    int qrow = b * 2048 + qt * 64 + wave * 16 + l16;
    const __bf16* qbase = qkv + (size_t)qrow * RS + h * 64;
    bf16x8 qf0 = *(const bf16x8*)(qbase + quad * 8);
    bf16x8 qf1 = *(const bf16x8*)(qbase + 32 + quad * 8);

    float l_i = 0.f;
    f32x4 o[4];
#pragma unroll
    for (int j = 0; j < 4; ++j) o[j] = (f32x4){0.f, 0.f, 0.f, 0.f};

    // stage tile 0 into buffer 0 (K rows = keys; V rows = dims)
#pragma unroll
    for (int i = 0; i < 2; ++i) {
      gld16(kbase + (size_t)(row0 + 32 * i) * RS,
            (char*)Kb[0] + (i * 256 + tid) * 16);
      gld16(vbase + (size_t)(row0 + 32 * i) * 2048,
            (char*)Vb[0] + (i * 256 + tid) * 16);
    }
    __syncthreads();

    for (int kt = 0; kt <= qt; ++kt) {
      const int cur = kt & 1;
      // prefetch tile kt+1 via DMA into the other buffer
      if (kt < qt) {
#pragma unroll
        for (int i = 0; i < 2; ++i) {
          gld16(kbase + (size_t)((kt + 1) * 64 + row0 + 32 * i) * RS,
                (char*)Kb[cur ^ 1] + (i * 256 + tid) * 16);
          gld16(vbase + (size_t)(row0 + 32 * i) * 2048 + (kt + 1) * 64,
                (char*)Vb[cur ^ 1] + (i * 256 + tid) * 16);
        }
      }

      // S^T = K Q^T : lane holds S^T[key=j*16+quad*4+r][qrow=wave*16+l16]
      f32x4 s[4];
#pragma unroll
      for (int j = 0; j < 4; ++j) s[j] = (f32x4){0.f, 0.f, 0.f, 0.f};
#pragma unroll
      for (int j = 0; j < 4; ++j) {
        bf16x8 kf0 = *(const bf16x8*)&Kb[cur][(j * 16 + l16) * 64 + ((quad * 8) ^ xr)];
        bf16x8 kf1 = *(const bf16x8*)&Kb[cur][(j * 16 + l16) * 64 + ((32 + quad * 8) ^ xr)];
        s[j] = MFMA_BF16(kf0, qf0, s[j]);
        s[j] = MFMA_BF16(kf1, qf1, s[j]);
      }

      // causal mask only on the diagonal tile (uniform branch)
      if (kt == qt) {
        int qg = wave * 16 + l16;
#pragma unroll
        for (int j = 0; j < 4; ++j)
#pragma unroll
          for (int r = 0; r < 4; ++r)
            if (j * 16 + quad * 4 + r > qg) s[j][r] = NEG_INF;
      }

      // P = exp2(S*SCL); scalar l accum (lane owns qrow=l16);
      // P^T reg layout -> contiguous b64 stores to Ps[qrow][key]
#pragma unroll
      for (int j = 0; j < 4; ++j) {
        bf16x4 pb;
#pragma unroll
        for (int r = 0; r < 4; ++r) {
          float p = __builtin_amdgcn_exp2f(s[j][r] * SCL);
          l_i += p;
          pb[r] = (__bf16)p;
        }
        *(bf16x4*)&Ps[wave][l16 * 72 + j * 16 + quad * 4] = pb;
      }

      // O += P V : A=P[qrow][key] from Ps (b128), B=V[dim][key] from Vb
#pragma unroll
      for (int ks = 0; ks < 2; ++ks) {
        bf16x8 pf = *(const bf16x8*)&Ps[wave][l16 * 72 + ks * 32 + quad * 8];
#pragma unroll
        for (int j = 0; j < 4; ++j) {
          bf16x8 vf = *(const bf16x8*)&Vb[cur][(j * 16 + l16) * 64 +
                                              ((ks * 32 + quad * 8) ^ xr)];
          o[j] = MFMA_BF16(pf, vf, o[j]);
        }
      }
      __syncthreads();  // single barrier per tile (drains DMA + Ps reads)
    }

    // l lives at lane l16 (all quads identical after xor-16/32 reduction)
    float lred = l_i;
    lred += __shfl_xor(lred, 16);
    lred += __shfl_xor(lred, 32);
    int orow = b * 2048 + qt * 64 + wave * 16 + quad * 4;
#pragma unroll
    for (int r = 0; r < 4; ++r) {
      float inv = 1.f / __shfl(lred, quad * 4 + r);
#pragma unroll
      for (int j = 0; j < 4; ++j)
        y[(size_t)(orow + r) * 1024 + h * 64 + j * 16 + l16] = (__bf16)(o[j][r] * inv);
    }
  }
}

// ---------------------------------------------------------------------------
extern "C" void kernel_launch(void* const* d_in, const int* in_sizes, int n_in,
                              void* d_out, int out_size, void* d_ws, size_t ws_size,
                              hipStream_t stream) {
  (void)in_sizes; (void)n_in; (void)out_size; (void)ws_size;
  const float* x      = (const float*)d_in[0];  // [2,2048,1024] fp32
  const float* w_attn = (const float*)d_in[1];  // [1024,3072]
  const float* b_attn = (const float*)d_in[2];  // [3072]
  const float* w_proj = (const float*)d_in[3];  // [1024,1024]
  const float* b_proj = (const float*)d_in[4];  // [1024]
  float* out = (float*)d_out;                   // [2,2048,1024] fp32

  __bf16* wt_attn = (__bf16*)d_ws;                       // [3072][1024]
  __bf16* wt_proj = wt_attn + (size_t)3072 * 1024;       // [1024][1024]
  __bf16* qkv     = wt_proj + (size_t)1024 * 1024;       // [4096][3072]
  __bf16* ybuf    = qkv + (size_t)4096 * 3072;           // [4096][1024]
  __bf16* vtbuf   = ybuf + (size_t)4096 * 1024;          // [32*64][2048]

  // x -> bf16, staged in ybuf (attention overwrites it later; same stream)
  cast_f32_bf16<<<4096 * 1024 / 2048, 256, 0, stream>>>(x, ybuf, 4096 * 1024);

  transpose_f32_bf16<<<dim3(3072 / 32, 1024 / 32), 256, 0, stream>>>(w_attn, wt_attn, 1024, 3072);
  transpose_f32_bf16<<<dim3(1024 / 32, 1024 / 32), 256, 0, stream>>>(w_proj, wt_proj, 1024, 1024);

  // qkv = x @ w_attn + b_attn; V columns written transposed into vtbuf
  // (8-phase 256x192 tile; grid 16x16 = 256 blocks = 1/CU)
  gemm_qkv_8ph<<<dim3(3072 / 192, 4096 / 256), 512, 0, stream>>>(
      ybuf, wt_attn, b_attn, qkv, vtbuf);

  // y = causal_attention(qkv, vt), overwrites ybuf (512 blocks, 33 iters each)
  attn_causal<<<dim3(2 * 16, 16), 256, 0, stream>>>(qkv, vtbuf, ybuf);

  // out = y @ w_proj + b_proj   (512 blocks, BM=64 for occupancy)
  gemm_bt_bias<64, float><<<dim3(1024 / BN, 4096 / 64), 256, 0, stream>>>(
      ybuf, wt_proj, b_proj, out, 4096, 1024, 1024);
}